// Round 9
// baseline (333.113 us; speedup 1.0000x reference)
//
#include <hip/hip_runtime.h>
#include <hip/hip_fp8.h>
#include <stdint.h>

// Problem constants (fixed by reference setup_inputs)
constexpr int N    = 8192;
constexpr int D    = 512;
constexpr int KEXT = 8;
constexpr int NCLS = 1000;
#define TAU_INV  14.285714285714285714f   // 1/0.07
#define SQRT_TI  3.7796447300922722f      // sqrt(1/0.07); folded into packed fp8

typedef long   long2_t __attribute__((ext_vector_type(2)));  // 16B = 2 fp8 MFMA operands
typedef float  f32x4   __attribute__((ext_vector_type(4)));

typedef __attribute__((address_space(1))) void gvoid;
typedef __attribute__((address_space(3))) void lvoid;

__device__ __forceinline__ uint32_t pack4_e4m3(float a, float b, float c, float d) {
    __hip_fp8_e4m3 A(a), B(b), C(c), D(d);   // OCP e4m3fn on gfx950
    return (uint32_t)A.__x | ((uint32_t)B.__x << 8) |
           ((uint32_t)C.__x << 16) | ((uint32_t)D.__x << 24);
}

// ---------------- fused prep: histogram + fp8 fragment-packing of q --------
// qf8 layout (validated R7/R8, absmax 0.0): 16B granule slot = (t*512 +
// ks2*64 + quad*16 + l15), t=16-row tile, ks2=64-wide K-macrostep. Bytes
// [0..8) hold q[t*16+l15][ks2*64+quad*8 ..+8)*SQRT_TI, bytes [8..16) the +32
// window. Band ib (8 tiles) is a CONTIGUOUS 64KB region -> linear LDS DMA.
__global__ void prep_k(const float* __restrict__ q, const int* __restrict__ y,
                       uint32_t* __restrict__ qf8, int* __restrict__ counts,
                       float* __restrict__ invy, float* __restrict__ pos,
                       float* __restrict__ neg) {
    const int b = blockIdx.x, tid = threadIdx.x;
    if (b == 0) {
        __shared__ int h[NCLS];
        for (int i = tid; i < NCLS; i += 256) h[i] = 0;
        __syncthreads();
        for (int i = tid; i < N; i += 256) atomicAdd(&h[y[i]], 1);
        __syncthreads();
        for (int i = tid; i < NCLS; i += 256) counts[i] = h[i];
        for (int i = tid; i < N; i += 256) invy[i] = 1.0f / (float)h[y[i]];
        return;
    }
    const int gid = (b - 1) * 256 + tid;     // over N*32 granules
    const int row = gid >> 5;                // source row of q
    const int c   = gid & 31;                // granule within row
    const int ks2 = c >> 2, quad = c & 3;
    const float* src = q + (size_t)row * D + ks2 * 64 + quad * 8;
    float4 v0 = *reinterpret_cast<const float4*>(src);
    float4 v1 = *reinterpret_cast<const float4*>(src + 4);
    float4 v2 = *reinterpret_cast<const float4*>(src + 32);
    float4 v3 = *reinterpret_cast<const float4*>(src + 36);
    uint4 o;
    o.x = pack4_e4m3(v0.x * SQRT_TI, v0.y * SQRT_TI, v0.z * SQRT_TI, v0.w * SQRT_TI);
    o.y = pack4_e4m3(v1.x * SQRT_TI, v1.y * SQRT_TI, v1.z * SQRT_TI, v1.w * SQRT_TI);
    o.z = pack4_e4m3(v2.x * SQRT_TI, v2.y * SQRT_TI, v2.z * SQRT_TI, v2.w * SQRT_TI);
    o.w = pack4_e4m3(v3.x * SQRT_TI, v3.y * SQRT_TI, v3.z * SQRT_TI, v3.w * SQRT_TI);
    const int t = row >> 4, l15 = row & 15;
    reinterpret_cast<uint4*>(qf8)[(size_t)t * 512 + ks2 * 64 + quad * 16 + l15] = o;
    if (gid < N) { pos[gid] = 0.f; neg[gid] = 0.f; }
}

// ---------------- band-sweep GEMM (q @ q^T) + fused contrastive epilogue ---
// R8 structure (64KB LDS A-band, B streamed from L2-resident qf8, register
// row-sums, 256 atomics/block) with the K-loop live set dieted to stop the
// scratch spills R8's 70MB WRITE_SIZE revealed: A-fragments single-buffered
// from LDS (imm-offset ds_read_b128), row labels read from LDS per epilogue.
__global__ __launch_bounds__(256, 2) void gemm_k(
        const uint32_t* __restrict__ qf8,
        const int* __restrict__ y,
        const float* __restrict__ invy,
        float* __restrict__ pos_sum,
        float* __restrict__ neg_sum) {
    __shared__ long2_t Asl[4096];       // 64KB: band's 8 tiles x 512 granules
    __shared__ int   yR[128];           // band labels
    __shared__ float redP[2][128];      // column-half partials
    __shared__ float redN[2][128];

    const int tid  = threadIdx.x;
    const int wave = tid >> 6;
    const int lane = tid & 63;
    const int quad = lane >> 4;
    const int l15  = lane & 15;

    const int ib     = blockIdx.x >> 3;       // row band 0..63
    const int jchunk = blockIdx.x & 7;        // 1024-col chunk
    const int ibase  = ib * 128;

    // ---- DMA A-band into LDS: pure linear 64KB copy ----
    {
        const uint32_t* src = qf8 + (size_t)ib * 16384;   // 4096 granules
#pragma unroll
        for (int it = 0; it < 16; it++) {
            const int idx = it * 256 + tid;
            __builtin_amdgcn_global_load_lds((gvoid*)(src + idx * 4),
                                             (lvoid*)(Asl + idx), 16, 0, 0);
        }
    }
    if (tid < 128) yR[tid] = y[ibase + tid];
    __syncthreads();   // DMA drained (compiler emits vmcnt(0) before barrier)

    // wave position: 2x2 waves over each 128x128 subtile
    const int wr = (wave >> 1) * 64;
    const int wc = (wave & 1) * 64;
    const int half = wave & 1;

    float posp[16], negp[16];
#pragma unroll
    for (int e = 0; e < 16; e++) { posp[e] = 0.f; negp[e] = 0.f; }

    const long2_t* fb = reinterpret_cast<const long2_t*>(qf8);
    // B fragment pointers for subtile 0 of this chunk
    const long2_t* pB[4];
#pragma unroll
    for (int m = 0; m < 4; m++)
        pB[m] = fb + (size_t)(jchunk * 64 + (wc >> 4) + m) * 512 + lane;

    // single LDS base for A: imm offsets m*512 + ks2*64 granules (<=31744B)
    const long2_t* As = Asl + (wr >> 4) * 512 + lane;

    for (int jt = 0; jt < 8; jt++) {
        const int j0 = jchunk * 1024 + jt * 128;

        // column metadata
        int   yjv[4];
        float icj[4];
#pragma unroll
        for (int mj = 0; mj < 4; mj++) {
            int jc = j0 + wc + mj * 16 + l15;
            yjv[mj] = y[jc];
            icj[mj] = invy[jc];
        }

        f32x4 acc[4][4];
#pragma unroll
        for (int a = 0; a < 4; a++)
#pragma unroll
            for (int c = 0; c < 4; c++) acc[a][c] = (f32x4)0.0f;

        // K-loop: B register double-buffered (global), A single (LDS imm)
        long2_t bf[2][4];
#pragma unroll
        for (int m = 0; m < 4; m++) bf[0][m] = pB[m][0];

#pragma unroll
        for (int ks2 = 0; ks2 < 8; ks2++) {
            const int cur = ks2 & 1, nxt = cur ^ 1;
            if (ks2 < 7) {
#pragma unroll
                for (int m = 0; m < 4; m++) bf[nxt][m] = pB[m][(ks2 + 1) * 64];
            }
            long2_t af[4];
#pragma unroll
            for (int m = 0; m < 4; m++) af[m] = As[m * 512 + ks2 * 64];
#pragma unroll
            for (int mi = 0; mi < 4; mi++)
#pragma unroll
                for (int mj = 0; mj < 4; mj++)
                    acc[mi][mj] = __builtin_amdgcn_mfma_f32_16x16x32_fp8_fp8(
                        af[mi].x, bf[cur][mj].x, acc[mi][mj], 0, 0, 0);
#pragma unroll
            for (int mi = 0; mi < 4; mi++)
#pragma unroll
                for (int mj = 0; mj < 4; mj++)
                    acc[mi][mj] = __builtin_amdgcn_mfma_f32_16x16x32_fp8_fp8(
                        af[mi].y, bf[cur][mj].y, acc[mi][mj], 0, 0, 0);
        }
#pragma unroll
        for (int m = 0; m < 4; m++) pB[m] += 4096;   // next 128 cols (8 tiles)

        // fused epilogue: acc holds sim/tau (sqrt(1/tau) folded into qf8)
#pragma unroll
        for (int mi = 0; mi < 4; mi++) {
#pragma unroll
            for (int r = 0; r < 4; r++) {
                const int il   = wr + mi * 16 + quad * 4 + r;   // C/D: row = quad*4+reg
                const int irow = ibase + il;
                const int myi  = yR[il];                        // LDS broadcast read
                float ps = 0.f, ns = 0.f;
#pragma unroll
                for (int mj = 0; mj < 4; mj++) {
                    const int jcol = j0 + wc + mj * 16 + l15;   // C/D: col = lane&15
                    float a    = acc[mi][mj][r];
                    float ex   = __expf(a);
                    bool  nz   = (a != 0.0f);                   // faithful masked_fill(x==0,-inf)
                    bool  same = (myi == yjv[mj]);
                    ps += (same && (irow != jcol) && nz) ? ex : 0.0f;
                    ns += (!same && nz) ? ex * icj[mj] : 0.0f;
                }
                posp[mi * 4 + r] += ps;
                negp[mi * 4 + r] += ns;
            }
        }
    }

    // ---- commit: 16-lane reduce -> LDS column-half combine -> 256 atomics ----
#pragma unroll
    for (int mi = 0; mi < 4; mi++) {
#pragma unroll
        for (int r = 0; r < 4; r++) {
            const int e = mi * 4 + r;
            float ps = posp[e], ns = negp[e];
#pragma unroll
            for (int off = 1; off < 16; off <<= 1) {
                ps += __shfl_xor(ps, off);
                ns += __shfl_xor(ns, off);
            }
            if (l15 == 0) {
                const int il = wr + mi * 16 + quad * 4 + r;
                redP[half][il] = ps;
                redN[half][il] = ns;
            }
        }
    }
    __syncthreads();
    if (tid < 128) {
        atomicAdd(&pos_sum[ibase + tid], redP[0][tid] + redP[1][tid]);
    } else if (tid < 256) {
        const int il = tid - 128;
        atomicAdd(&neg_sum[ibase + il], redN[0][il] + redN[1][il]);
    }
}

// ---------------- per-row finalize: k_sims (fp32, float4 loads) ------------
__global__ void finalize_k(const float* __restrict__ q, const float* __restrict__ kmat,
                           const int* __restrict__ y, const int* __restrict__ counts,
                           const float* __restrict__ pos_sum, const float* __restrict__ neg_sum,
                           float* __restrict__ loss) {
    const int wave = threadIdx.x >> 6, lane = threadIdx.x & 63;
    const int i = blockIdx.x * 4 + wave;

    const float4* q4 = reinterpret_cast<const float4*>(q) + (size_t)i * 128;
    const float4* k4 = reinterpret_cast<const float4*>(kmat) + (size_t)i * KEXT * 128;
    float4 qa = q4[lane], qb = q4[lane + 64];

    float esum = 0.f;
    for (int kk = 0; kk < KEXT; kk++) {
        float4 ka = k4[(size_t)kk * 128 + lane];
        float4 kb = k4[(size_t)kk * 128 + lane + 64];
        float p = qa.x * ka.x;
        p = fmaf(qa.y, ka.y, p); p = fmaf(qa.z, ka.z, p); p = fmaf(qa.w, ka.w, p);
        p = fmaf(qb.x, kb.x, p); p = fmaf(qb.y, kb.y, p);
        p = fmaf(qb.z, kb.z, p); p = fmaf(qb.w, kb.w, p);
#pragma unroll
        for (int off = 1; off < 64; off <<= 1) p += __shfl_xor(p, off);
        esum += __expf(p * TAU_INV);
    }
    if (lane == 0) {
        float num = logf(esum + pos_sum[i]);
        float den = logf(neg_sum[i]);
        float cnt = (float)(counts[y[i]] - 1 + KEXT);  // same_class_counts, label-only
        loss[i] = -(num - den) / cnt;
    }
}

__global__ void reduce_k(const float* __restrict__ loss, float* __restrict__ out) {
    __shared__ float part[16];
    int tid = threadIdx.x;   // 1024 threads
    float s = 0.f;
    for (int i = tid; i < N; i += 1024) s += loss[i];
#pragma unroll
    for (int off = 1; off < 64; off <<= 1) s += __shfl_xor(s, off);
    if ((tid & 63) == 0) part[tid >> 6] = s;
    __syncthreads();
    if (tid < 16) {
        float v = part[tid];
#pragma unroll
        for (int off = 1; off < 16; off <<= 1) v += __shfl_xor(v, off);
        if (tid == 0) out[0] = v / (float)N;
    }
}

// ---------------- launch ----------------
extern "C" void kernel_launch(void* const* d_in, const int* in_sizes, int n_in,
                              void* d_out, int out_size, void* d_ws, size_t ws_size,
                              hipStream_t stream) {
    const float* q    = (const float*)d_in[0];
    const float* kmat = (const float*)d_in[1];
    const int*   y    = (const int*)d_in[2];
    float* out = (float*)d_out;

    char* ws = (char*)d_ws;
    uint32_t* qf8  = (uint32_t*)ws;                 // 4 MB: packed fp8 fragments
    int*   counts  = (int*)  (ws + 4194304);        // 1000 ints
    float* invy    = (float*)(ws + 4198400);        // N floats: 1/count[y[j]]
    float* pos     = (float*)(ws + 4231168);        // N floats
    float* neg     = (float*)(ws + 4263936);        // N floats
    float* loss    = (float*)(ws + 4296704);        // N floats

    prep_k    <<<1 + (N * 32) / 256, 256, 0, stream>>>(q, y, qf8, counts, invy, pos, neg);
    gemm_k    <<<512, 256, 0, stream>>>(qf8, y, invy, pos, neg);
    finalize_k<<<N / 4, 256, 0, stream>>>(q, kmat, y, counts, pos, neg, loss);
    reduce_k  <<<1, 1024, 0, stream>>>(loss, out);
}